// Round 11
// baseline (231.845 us; speedup 1.0000x reference)
//
#include <hip/hip_runtime.h>
#include <hip/hip_cooperative_groups.h>

namespace cg = cooperative_groups;

#define TPB 1024
#define GRID 256   // 64 b * 4 n-chunks(512 n); 1 block/CU -> coop always fits

// r10 post-mortem: 48% VALUBusy; residue = 3 barriers/layer + two phases
// where 7/8 of threads idle. This round: wave0 owns wait+gather+fold (its 64
// lanes fold one (u,h) bias pair each, ~50 FMA), same-wave LDS ordering, so
// layer = phase1 || wave0-prep -> SYNC -> phase4 -> SYNC -> wave0 publish.
// Bias LDS layout [u][16h] -> ds_read_b128 in phase4. fin folded into wave0.

__global__ void __launch_bounds__(TPB) risnet_kernel(
    const float* __restrict__ channel,
    const float* __restrict__ We1, const float* __restrict__ be1,
    const float* __restrict__ We,  const float* __restrict__ be,
    const float* __restrict__ Wo1, const float* __restrict__ bo1,
    const float* __restrict__ Wo,  const float* __restrict__ bo,
    const float* __restrict__ W8,  const float* __restrict__ b8,
    float* __restrict__ out, float* __restrict__ part, int* __restrict__ flags)
{
  const int tid   = threadIdx.x;
  const int lane  = tid & 63;
  const int wv    = tid >> 6;                 // 0..15
  const int p     = tid & 1;                  // user-half: owns users 2p, 2p+1
  const int b     = blockIdx.x >> 2;          // 0..63
  const int chunk = blockIdx.x & 3;           // 0..3
  const int n     = (chunk << 9) | (tid >> 1);// 0..2047

  __shared__ __align__(16) float biasEl[4][16];  // [u][h]
  __shared__ __align__(16) float biasOl[4][16];
  __shared__ float red[16][64];                  // per-wave sums: conv*32 + j*4 + u
  __shared__ float gvs[64];                      // per-b means: ego-g 0..31, opp-g 32..63
  __shared__ float fin;

  if (tid == 0)
    __hip_atomic_store(&flags[blockIdx.x], 0, __ATOMIC_RELAXED, __HIP_MEMORY_SCOPE_AGENT);

  // per-thread channel slice: ch_[q][f] = user 2p+q
  float ch_[2][4];
#pragma unroll
  for (int q = 0; q < 2; ++q)
#pragma unroll
    for (int f = 0; f < 4; ++f)
      ch_[q][f] = channel[((b*4 + 2*p + q)*4 + f)*2048 + n];

  cg::grid_group grid = cg::this_grid();
  grid.sync();   // all flags zeroed before any block can set/wait (replay safety)

  float el_[2][8], ol_[2][8];

#define BFLY(a0, a1) { \
  a0 += __shfl_xor(a0, 2, 64);  a1 += __shfl_xor(a1, 2, 64);  \
  a0 += __shfl_xor(a0, 4, 64);  a1 += __shfl_xor(a1, 4, 64);  \
  a0 += __shfl_xor(a0, 8, 64);  a1 += __shfl_xor(a1, 8, 64);  \
  a0 += __shfl_xor(a0, 16, 64); a1 += __shfl_xor(a1, 16, 64); \
  a0 += __shfl_xor(a0, 32, 64); a1 += __shfl_xor(a1, 32, 64); }

  // ---------------- layer 0 (Cin = 4, feats = ch) ----------------
  {
    float opl[2][8];
#pragma unroll
    for (int h = 0; h < 16; ++h) {
      const float4 w = *(const float4*)(We1 + h*4);
      const float bs = be1[h];
      float a0 = fmaxf(bs + w.x*ch_[0][0] + w.y*ch_[0][1] + w.z*ch_[0][2] + w.w*ch_[0][3], 0.f);
      float a1 = fmaxf(bs + w.x*ch_[1][0] + w.y*ch_[1][1] + w.z*ch_[1][2] + w.w*ch_[1][3], 0.f);
      if (h < 8) { el_[0][h] = a0; el_[1][h] = a1; }
      else {
        BFLY(a0, a1);
        if (lane < 2) { red[wv][(h-8)*4 + 2*lane + 0] = a0; red[wv][(h-8)*4 + 2*lane + 1] = a1; }
      }
    }
#pragma unroll
    for (int h = 0; h < 16; ++h) {
      const float4 w = *(const float4*)(Wo1 + h*4);
      const float bs = bo1[h];
      float a0 = fmaxf(bs + w.x*ch_[0][0] + w.y*ch_[0][1] + w.z*ch_[0][2] + w.w*ch_[0][3], 0.f);
      float a1 = fmaxf(bs + w.x*ch_[1][0] + w.y*ch_[1][1] + w.z*ch_[1][2] + w.w*ch_[1][3], 0.f);
      if (h < 8) { opl[0][h] = a0; opl[1][h] = a1; }
      else {
        BFLY(a0, a1);
        if (lane < 2) { red[wv][32 + (h-8)*4 + 2*lane + 0] = a0; red[wv][32 + (h-8)*4 + 2*lane + 1] = a1; }
      }
    }
#pragma unroll
    for (int j = 0; j < 8; ++j) {
      const float s2 = opl[0][j] + opl[1][j];
      const float s4 = s2 + __shfl_xor(s2, 1, 64);
      ol_[0][j] = (s4 - opl[0][j]) * (1.f/3.f);
      ol_[1][j] = (s4 - opl[1][j]) * (1.f/3.f);
    }
  }
  __syncthreads();
  if (wv == 0) {
    float s = 0.f;
#pragma unroll
    for (int w = 0; w < 16; ++w) s += red[w][lane];
    __hip_atomic_store(&part[((0*64 + b)*4 + chunk)*64 + lane], s,
                       __ATOMIC_RELAXED, __HIP_MEMORY_SCOPE_AGENT);
  }
  if (tid == 0)
    __hip_atomic_store(&flags[blockIdx.x], 1, __ATOMIC_RELEASE, __HIP_MEMORY_SCOPE_AGENT);

  // ---------------- layers 1..6 (Cin = 36) ----------------
  for (int L = 1; L < 7; ++L) {
    const float* __restrict__ wEl = We + (L-1)*576;   // wave-uniform -> s_loads
    const float* __restrict__ wOl = Wo + (L-1)*576;
    const int par_r = (L-1) & 1;
    const int par_w = L & 1;

    // --- phase 1: LOCAL conv accumulators (no cross-block data) ---
    float accE[2][16], accO[2][16];
#pragma unroll
    for (int h = 0; h < 16; ++h) {
      const float4* wr = (const float4*)(wEl + h*36);
      const float4 w0 = wr[0], w1 = wr[1], w2 = wr[2], w5 = wr[5], w6 = wr[6];
#pragma unroll
      for (int q = 0; q < 2; ++q) {
        float v = 0.f;
        v += w0.x*ch_[q][0] + w0.y*ch_[q][1] + w0.z*ch_[q][2] + w0.w*ch_[q][3];
        v += w1.x*el_[q][0] + w1.y*el_[q][1] + w1.z*el_[q][2] + w1.w*el_[q][3];
        v += w2.x*el_[q][4] + w2.y*el_[q][5] + w2.z*el_[q][6] + w2.w*el_[q][7];
        v += w5.x*ol_[q][0] + w5.y*ol_[q][1] + w5.z*ol_[q][2] + w5.w*ol_[q][3];
        v += w6.x*ol_[q][4] + w6.y*ol_[q][5] + w6.z*ol_[q][6] + w6.w*ol_[q][7];
        accE[q][h] = v;
      }
    }
#pragma unroll
    for (int h = 0; h < 16; ++h) {
      const float4* wr = (const float4*)(wOl + h*36);
      const float4 w0 = wr[0], w1 = wr[1], w2 = wr[2], w5 = wr[5], w6 = wr[6];
#pragma unroll
      for (int q = 0; q < 2; ++q) {
        float v = 0.f;
        v += w0.x*ch_[q][0] + w0.y*ch_[q][1] + w0.z*ch_[q][2] + w0.w*ch_[q][3];
        v += w1.x*el_[q][0] + w1.y*el_[q][1] + w1.z*el_[q][2] + w1.w*el_[q][3];
        v += w2.x*el_[q][4] + w2.y*el_[q][5] + w2.z*el_[q][6] + w2.w*el_[q][7];
        v += w5.x*ol_[q][0] + w5.y*ol_[q][1] + w5.z*ol_[q][2] + w5.w*ol_[q][3];
        v += w6.x*ol_[q][4] + w6.y*ol_[q][5] + w6.z*ol_[q][6] + w6.w*ol_[q][7];
        accO[q][h] = v;
      }
    }

    // --- wave0: wait on b-group, gather means, fold bias (no barriers) ---
    if (wv == 0) {
      const int gi = (b << 2) | (lane & 3);
      for (;;) {
        int f = __hip_atomic_load(&flags[gi], __ATOMIC_ACQUIRE, __HIP_MEMORY_SCOPE_AGENT);
        if (__all(f >= L)) break;
        __builtin_amdgcn_s_sleep(1);
      }
      float s = 0.f;
#pragma unroll
      for (int k = 0; k < 4; ++k)
        s += __hip_atomic_load(&part[((par_r*64 + b)*4 + k)*64 + lane],
                               __ATOMIC_RELAXED, __HIP_MEMORY_SCOPE_AGENT);
      gvs[lane] = s * (1.f/2048.f);
      // fold: this lane owns (u, h) for BOTH convs
      const int u = lane & 3;
      const int h = lane >> 2;
      float bE = be[(L-1)*16 + h];
      float bO = bo[(L-1)*16 + h];
#pragma unroll
      for (int j = 0; j < 8; ++j) {
        const float eg = gvs[j*4 + u];
        const float so = gvs[32+j*4+0] + gvs[32+j*4+1] + gvs[32+j*4+2] + gvs[32+j*4+3];
        const float og = (so - gvs[32 + j*4 + u]) * (1.f/3.f);
        bE += wEl[h*36 + 12 + j] * eg + wEl[h*36 + 28 + j] * og;
        bO += wOl[h*36 + 12 + j] * eg + wOl[h*36 + 28 + j] * og;
      }
      biasEl[u][h] = bE;
      biasOl[u][h] = bO;
    }
    __syncthreads();

    // --- phase 4: add bias, relu (in place), reduce h>=8, LOO, commit ---
#pragma unroll
    for (int q = 0; q < 2; ++q) {
      const int u = 2*p + q;
#pragma unroll
      for (int h = 0; h < 16; ++h) {
        accE[q][h] = fmaxf(accE[q][h] + biasEl[u][h], 0.f);
        accO[q][h] = fmaxf(accO[q][h] + biasOl[u][h], 0.f);
      }
    }
#pragma unroll
    for (int h = 8; h < 16; ++h) {
      float a0 = accE[0][h], a1 = accE[1][h];
      BFLY(a0, a1);
      if (lane < 2) { red[wv][(h-8)*4 + 2*lane + 0] = a0; red[wv][(h-8)*4 + 2*lane + 1] = a1; }
    }
#pragma unroll
    for (int h = 8; h < 16; ++h) {
      float a0 = accO[0][h], a1 = accO[1][h];
      BFLY(a0, a1);
      if (lane < 2) { red[wv][32 + (h-8)*4 + 2*lane + 0] = a0; red[wv][32 + (h-8)*4 + 2*lane + 1] = a1; }
    }
#pragma unroll
    for (int j = 0; j < 8; ++j) {
      const float s2 = accO[0][j] + accO[1][j];
      const float s4 = s2 + __shfl_xor(s2, 1, 64);
      ol_[0][j] = (s4 - accO[0][j]) * (1.f/3.f);
      ol_[1][j] = (s4 - accO[1][j]) * (1.f/3.f);
      el_[0][j] = accE[0][j];
      el_[1][j] = accE[1][j];
    }
    __syncthreads();

    // --- wave0: publish block partials, raise flag ---
    if (wv == 0) {
      float s = 0.f;
#pragma unroll
      for (int w = 0; w < 16; ++w) s += red[w][lane];
      __hip_atomic_store(&part[((par_w*64 + b)*4 + chunk)*64 + lane], s,
                         __ATOMIC_RELAXED, __HIP_MEMORY_SCOPE_AGENT);
    }
    if (tid == 0)
      __hip_atomic_store(&flags[blockIdx.x], L + 1, __ATOMIC_RELEASE, __HIP_MEMORY_SCOPE_AGENT);
  }

  // ---------------- final 1x1 conv + mean over users ----------------
  if (wv == 0) {   // layer 6 wrote parity 0
    const int gi = (b << 2) | (lane & 3);
    for (;;) {
      int f = __hip_atomic_load(&flags[gi], __ATOMIC_ACQUIRE, __HIP_MEMORY_SCOPE_AGENT);
      if (__all(f >= 7)) break;
      __builtin_amdgcn_s_sleep(1);
    }
    float s = 0.f;
#pragma unroll
    for (int k = 0; k < 4; ++k)
      s += __hip_atomic_load(&part[((0*64 + b)*4 + k)*64 + lane],
                             __ATOMIC_RELAXED, __HIP_MEMORY_SCOPE_AGENT);
    gvs[lane] = s * (1.f/2048.f);
    if (lane == 0) {
      float sf = b8[0];
#pragma unroll
      for (int j = 0; j < 8; ++j) {
        const float so = gvs[32+j*4+0] + gvs[32+j*4+1] + gvs[32+j*4+2] + gvs[32+j*4+3];
#pragma unroll
        for (int u = 0; u < 4; ++u) {
          const float eg = gvs[j*4 + u];
          const float og = (so - gvs[32 + j*4 + u]) * (1.f/3.f);
          sf += 0.25f * (W8[12 + j] * eg + W8[28 + j] * og);
        }
      }
      fin = sf;
    }
  }
  __syncthreads();
  float t = 0.f;
#pragma unroll
  for (int q = 0; q < 2; ++q) {
    float v = 0.f;
#pragma unroll
    for (int c = 0; c < 4; ++c) v += W8[c] * ch_[q][c];
#pragma unroll
    for (int j = 0; j < 8; ++j) v += W8[4 + j] * el_[q][j] + W8[20 + j] * ol_[q][j];
    t += v;
  }
  t += __shfl_xor(t, 1, 64);   // sum over all 4 users
  if (p == 0)
    out[b*2048 + n] = (fin + 0.25f * t) * 3.14159265358979f;
}

extern "C" void kernel_launch(void* const* d_in, const int* in_sizes, int n_in,
                              void* d_out, int out_size, void* d_ws, size_t ws_size,
                              hipStream_t stream) {
  const float* channel = (const float*)d_in[0];
  const float* We1 = (const float*)d_in[1];
  const float* be1 = (const float*)d_in[2];
  const float* We  = (const float*)d_in[3];
  const float* be  = (const float*)d_in[4];
  const float* Wo1 = (const float*)d_in[5];
  const float* bo1 = (const float*)d_in[6];
  const float* Wo  = (const float*)d_in[7];
  const float* bo  = (const float*)d_in[8];
  const float* W8  = (const float*)d_in[9];
  const float* b8  = (const float*)d_in[10];
  float* out  = (float*)d_out;
  float* part = (float*)d_ws;                       // 2*64*4*64 floats = 131072 B
  int*   flags = (int*)((char*)d_ws + 131072);      // 256 ints

  void* args[] = { (void*)&channel, (void*)&We1, (void*)&be1, (void*)&We, (void*)&be,
                   (void*)&Wo1, (void*)&bo1, (void*)&Wo, (void*)&bo,
                   (void*)&W8, (void*)&b8, (void*)&out, (void*)&part, (void*)&flags };
  hipLaunchCooperativeKernel((void*)risnet_kernel, dim3(GRID), dim3(TPB), args, 0, stream);
}

// Round 12
// 190.232 us; speedup vs baseline: 1.2188x; 1.2188x over previous
//
#include <hip/hip_runtime.h>
#include <hip/hip_cooperative_groups.h>

namespace cg = cooperative_groups;

#define TPB 1024
#define GRID 256   // coop capacity on this stack is <=256 blocks (r2/r7 both
                   // silently no-op'd at 512). Never exceed 256.

// r11 post-mortem: wave0-fold restructure spilled (WRITE 1->41MB) -> revert to
// r10 phases. This round, 3 safe cuts: (1) XCD co-location: b-group's 4 blocks
// share B%8 so flag/part sync stays in one XCD's L2; (2) 3-level butterfly
// (masks 2,4,8) + red[64][64]: -64 DS swizzles/thread/layer, publish wave does
// 64 conflict-free column reads; (3) drop trailing publish barrier (release
// store orders part->flag; red reuse guarded by next fold barrier).

__global__ void __launch_bounds__(TPB) risnet_kernel(
    const float* __restrict__ channel,
    const float* __restrict__ We1, const float* __restrict__ be1,
    const float* __restrict__ We,  const float* __restrict__ be,
    const float* __restrict__ Wo1, const float* __restrict__ bo1,
    const float* __restrict__ Wo,  const float* __restrict__ bo,
    const float* __restrict__ W8,  const float* __restrict__ b8,
    float* __restrict__ out, float* __restrict__ part, int* __restrict__ flags)
{
  const int tid   = threadIdx.x;
  const int lane  = tid & 63;
  const int wv    = tid >> 6;                 // 0..15
  const int p     = tid & 1;                  // user-half: owns users 2p, 2p+1
  const int B     = blockIdx.x;
  const int b     = (B & 7) * 8 + ((B >> 3) & 7);  // same B%8 (XCD) per b-group
  const int chunk = B >> 6;                   // 0..3
  const int n     = (chunk << 9) | (tid >> 1);// 0..2047

  __shared__ __align__(16) float biasE[16][4];
  __shared__ __align__(16) float biasO[16][4];
  __shared__ float red[64][64];                 // [row=wv*4+grp][conv*32+j*4+u]
  __shared__ float gv[64];                      // per-b means: ego-g 0..31, opp-g 32..63
  __shared__ float fin;

  if (tid == 0)
    __hip_atomic_store(&flags[B], 0, __ATOMIC_RELAXED, __HIP_MEMORY_SCOPE_AGENT);

  // per-thread channel slice: ch_[q][f] = user 2p+q
  float ch_[2][4];
#pragma unroll
  for (int q = 0; q < 2; ++q)
#pragma unroll
    for (int f = 0; f < 4; ++f)
      ch_[q][f] = channel[((b*4 + 2*p + q)*4 + f)*2048 + n];

  cg::grid_group grid = cg::this_grid();
  grid.sync();   // all flags zeroed before any block can set/wait (replay safety)

  float el_[2][8], ol_[2][8];

  // 3-level parity-preserving reduce: sums over the 8 same-parity lanes of
  // each 16-lane group. Writer lanes: (lane&15)<2; row = wv*4 + (lane>>4).
#define BFLY3(a0, a1) { \
  a0 += __shfl_xor(a0, 2, 64);  a1 += __shfl_xor(a1, 2, 64);  \
  a0 += __shfl_xor(a0, 4, 64);  a1 += __shfl_xor(a1, 4, 64);  \
  a0 += __shfl_xor(a0, 8, 64);  a1 += __shfl_xor(a1, 8, 64); }

#define RED_W(base_col, a0, a1) \
  if ((lane & 15) < 2) { \
    red[(wv<<2)|(lane>>4)][(base_col) + 2*(lane&1) + 0] = a0; \
    red[(wv<<2)|(lane>>4)][(base_col) + 2*(lane&1) + 1] = a1; }

  // publish partials for layer L (red[] complete) then raise own flag.
  // NO trailing barrier: release store orders part->flag; red reuse is
  // guarded by the next layer's fold barrier (wave0 reads finish first).
#define PUBLISH(Lpar, Lval) { \
  __syncthreads(); \
  if (tid < 64) { \
    float s = 0.f; \
    _Pragma("unroll") for (int r = 0; r < 64; ++r) s += red[r][tid]; \
    __hip_atomic_store(&part[(((Lpar)*64 + b)*4 + chunk)*64 + tid], s, \
                       __ATOMIC_RELAXED, __HIP_MEMORY_SCOPE_AGENT); \
  } \
  if (tid == 0) \
    __hip_atomic_store(&flags[B], (Lval), __ATOMIC_RELEASE, __HIP_MEMORY_SCOPE_AGENT); }

  // wave 0 spins until the 4 blocks of THIS b-group reach tgt, then gathers.
  // Group members: (B & 63) | (k<<6), k=0..3 -- all on this block's XCD.
#define WAIT_GATHER(Lpar, tgt) \
  if (tid < 64) { \
    const int gi = (B & 63) | ((lane & 3) << 6); \
    for (;;) { \
      int f = __hip_atomic_load(&flags[gi], __ATOMIC_ACQUIRE, __HIP_MEMORY_SCOPE_AGENT); \
      if (__all(f >= (tgt))) break; \
      __builtin_amdgcn_s_sleep(1); \
    } \
    float s = 0.f; \
    _Pragma("unroll") for (int k = 0; k < 4; ++k) \
      s += __hip_atomic_load(&part[(((Lpar)*64 + b)*4 + k)*64 + lane], \
                             __ATOMIC_RELAXED, __HIP_MEMORY_SCOPE_AGENT); \
    gv[lane] = s * (1.f/2048.f); \
  }

  // ---------------- layer 0 (Cin = 4, feats = ch) ----------------
  {
    float opl[2][8];
#pragma unroll
    for (int h = 0; h < 16; ++h) {
      const float4 w = *(const float4*)(We1 + h*4);
      const float bs = be1[h];
      float a0 = fmaxf(bs + w.x*ch_[0][0] + w.y*ch_[0][1] + w.z*ch_[0][2] + w.w*ch_[0][3], 0.f);
      float a1 = fmaxf(bs + w.x*ch_[1][0] + w.y*ch_[1][1] + w.z*ch_[1][2] + w.w*ch_[1][3], 0.f);
      if (h < 8) { el_[0][h] = a0; el_[1][h] = a1; }
      else { BFLY3(a0, a1); RED_W((h-8)*4, a0, a1); }
    }
#pragma unroll
    for (int h = 0; h < 16; ++h) {
      const float4 w = *(const float4*)(Wo1 + h*4);
      const float bs = bo1[h];
      float a0 = fmaxf(bs + w.x*ch_[0][0] + w.y*ch_[0][1] + w.z*ch_[0][2] + w.w*ch_[0][3], 0.f);
      float a1 = fmaxf(bs + w.x*ch_[1][0] + w.y*ch_[1][1] + w.z*ch_[1][2] + w.w*ch_[1][3], 0.f);
      if (h < 8) { opl[0][h] = a0; opl[1][h] = a1; }
      else { BFLY3(a0, a1); RED_W(32 + (h-8)*4, a0, a1); }
    }
#pragma unroll
    for (int j = 0; j < 8; ++j) {
      const float s2 = opl[0][j] + opl[1][j];
      const float s4 = s2 + __shfl_xor(s2, 1, 64);
      ol_[0][j] = (s4 - opl[0][j]) * (1.f/3.f);
      ol_[1][j] = (s4 - opl[1][j]) * (1.f/3.f);
    }
  }
  PUBLISH(0, 1)

  // ---------------- layers 1..6 (Cin = 36) ----------------
  for (int L = 1; L < 7; ++L) {
    const float* __restrict__ wEl = We + (L-1)*576;   // wave-uniform -> s_loads
    const float* __restrict__ wOl = Wo + (L-1)*576;
    const int par_r = (L-1) & 1;
    const int par_w = L & 1;

    // --- phase 1: LOCAL conv accumulators (no cross-block data) ---
    float accE[2][16], accO[2][16];
#pragma unroll
    for (int h = 0; h < 16; ++h) {
      const float4* wr = (const float4*)(wEl + h*36);
      const float4 w0 = wr[0], w1 = wr[1], w2 = wr[2], w5 = wr[5], w6 = wr[6];
#pragma unroll
      for (int q = 0; q < 2; ++q) {
        float v = 0.f;
        v += w0.x*ch_[q][0] + w0.y*ch_[q][1] + w0.z*ch_[q][2] + w0.w*ch_[q][3];
        v += w1.x*el_[q][0] + w1.y*el_[q][1] + w1.z*el_[q][2] + w1.w*el_[q][3];
        v += w2.x*el_[q][4] + w2.y*el_[q][5] + w2.z*el_[q][6] + w2.w*el_[q][7];
        v += w5.x*ol_[q][0] + w5.y*ol_[q][1] + w5.z*ol_[q][2] + w5.w*ol_[q][3];
        v += w6.x*ol_[q][4] + w6.y*ol_[q][5] + w6.z*ol_[q][6] + w6.w*ol_[q][7];
        accE[q][h] = v;
      }
    }
#pragma unroll
    for (int h = 0; h < 16; ++h) {
      const float4* wr = (const float4*)(wOl + h*36);
      const float4 w0 = wr[0], w1 = wr[1], w2 = wr[2], w5 = wr[5], w6 = wr[6];
#pragma unroll
      for (int q = 0; q < 2; ++q) {
        float v = 0.f;
        v += w0.x*ch_[q][0] + w0.y*ch_[q][1] + w0.z*ch_[q][2] + w0.w*ch_[q][3];
        v += w1.x*el_[q][0] + w1.y*el_[q][1] + w1.z*el_[q][2] + w1.w*el_[q][3];
        v += w2.x*el_[q][4] + w2.y*el_[q][5] + w2.z*el_[q][6] + w2.w*el_[q][7];
        v += w5.x*ol_[q][0] + w5.y*ol_[q][1] + w5.z*ol_[q][2] + w5.w*ol_[q][3];
        v += w6.x*ol_[q][4] + w6.y*ol_[q][5] + w6.z*ol_[q][6] + w6.w*ol_[q][7];
        accO[q][h] = v;
      }
    }

    // --- phase 2: wait on own b-group + gather means ---
    WAIT_GATHER(par_r, L)
    __syncthreads();

    // --- phase 3: fold eg/og into per-(conv,u,h) bias ---
    if (tid < 128) {
      const int cv = tid >> 6;
      const int rr = tid & 63;
      const int u  = rr & 3;
      const int h  = rr >> 2;
      const float* W = cv ? wOl : wEl;
      float bias = cv ? bo[(L-1)*16 + h] : be[(L-1)*16 + h];
#pragma unroll
      for (int j = 0; j < 8; ++j) {
        const float eg = gv[j*4 + u];
        const float so = gv[32+j*4+0] + gv[32+j*4+1] + gv[32+j*4+2] + gv[32+j*4+3];
        const float og = (so - gv[32 + j*4 + u]) * (1.f/3.f);
        bias += W[h*36 + 12 + j] * eg + W[h*36 + 28 + j] * og;
      }
      if (cv) biasO[h][u] = bias; else biasE[h][u] = bias;
    }
    __syncthreads();

    // --- phase 4: add bias, relu, reduce h>=8, LOO, commit ---
    float opl[2][8];
#pragma unroll
    for (int h = 0; h < 16; ++h) {
      float a0 = fmaxf(accE[0][h] + biasE[h][2*p + 0], 0.f);
      float a1 = fmaxf(accE[1][h] + biasE[h][2*p + 1], 0.f);
      if (h < 8) { el_[0][h] = a0; el_[1][h] = a1; }
      else { BFLY3(a0, a1); RED_W((h-8)*4, a0, a1); }
    }
#pragma unroll
    for (int h = 0; h < 16; ++h) {
      float a0 = fmaxf(accO[0][h] + biasO[h][2*p + 0], 0.f);
      float a1 = fmaxf(accO[1][h] + biasO[h][2*p + 1], 0.f);
      if (h < 8) { opl[0][h] = a0; opl[1][h] = a1; }
      else { BFLY3(a0, a1); RED_W(32 + (h-8)*4, a0, a1); }
    }
#pragma unroll
    for (int j = 0; j < 8; ++j) {
      const float s2 = opl[0][j] + opl[1][j];
      const float s4 = s2 + __shfl_xor(s2, 1, 64);
      ol_[0][j] = (s4 - opl[0][j]) * (1.f/3.f);
      ol_[1][j] = (s4 - opl[1][j]) * (1.f/3.f);
    }
    PUBLISH(par_w, L + 1)
  }

  // ---------------- final 1x1 conv + mean over users ----------------
  WAIT_GATHER(0, 7)   // layer 6 wrote parity 0
  __syncthreads();
  if (tid == 0) {
    float s = b8[0];
#pragma unroll
    for (int j = 0; j < 8; ++j) {
      const float so = gv[32+j*4+0] + gv[32+j*4+1] + gv[32+j*4+2] + gv[32+j*4+3];
#pragma unroll
      for (int u = 0; u < 4; ++u) {
        const float eg = gv[j*4 + u];
        const float og = (so - gv[32 + j*4 + u]) * (1.f/3.f);
        s += 0.25f * (W8[12 + j] * eg + W8[28 + j] * og);
      }
    }
    fin = s;
  }
  __syncthreads();
  float t = 0.f;
#pragma unroll
  for (int q = 0; q < 2; ++q) {
    float v = 0.f;
#pragma unroll
    for (int c = 0; c < 4; ++c) v += W8[c] * ch_[q][c];
#pragma unroll
    for (int j = 0; j < 8; ++j) v += W8[4 + j] * el_[q][j] + W8[20 + j] * ol_[q][j];
    t += v;
  }
  t += __shfl_xor(t, 1, 64);   // sum over all 4 users
  if (p == 0)
    out[b*2048 + n] = (fin + 0.25f * t) * 3.14159265358979f;
}

extern "C" void kernel_launch(void* const* d_in, const int* in_sizes, int n_in,
                              void* d_out, int out_size, void* d_ws, size_t ws_size,
                              hipStream_t stream) {
  const float* channel = (const float*)d_in[0];
  const float* We1 = (const float*)d_in[1];
  const float* be1 = (const float*)d_in[2];
  const float* We  = (const float*)d_in[3];
  const float* be  = (const float*)d_in[4];
  const float* Wo1 = (const float*)d_in[5];
  const float* bo1 = (const float*)d_in[6];
  const float* Wo  = (const float*)d_in[7];
  const float* bo  = (const float*)d_in[8];
  const float* W8  = (const float*)d_in[9];
  const float* b8  = (const float*)d_in[10];
  float* out  = (float*)d_out;
  float* part = (float*)d_ws;                       // 2*64*4*64 floats = 131072 B
  int*   flags = (int*)((char*)d_ws + 131072);      // 256 ints

  void* args[] = { (void*)&channel, (void*)&We1, (void*)&be1, (void*)&We, (void*)&be,
                   (void*)&Wo1, (void*)&bo1, (void*)&Wo, (void*)&bo,
                   (void*)&W8, (void*)&b8, (void*)&out, (void*)&part, (void*)&flags };
  hipLaunchCooperativeKernel((void*)risnet_kernel, dim3(GRID), dim3(TPB), args, 0, stream);
}